// Round 6
// baseline (858.303 us; speedup 1.0000x reference)
//
#include <hip/hip_runtime.h>

#define N_ROWS 32768   // BS*SEQ
#define N_CODES 8192
#define DIM 256
#define KV 512         // packed K per operand (hi || lo)
#define NSTEP 12       // virtual K = 768, BK = 64
#define TWO_EPS 4e-6f  // > 2x sup error bound (~1.5e-6) of bf16-split distance

typedef __attribute__((ext_vector_type(8))) short bf16x8;
typedef __attribute__((ext_vector_type(4))) float f32x4;
typedef __attribute__((ext_vector_type(8))) unsigned short u16x8;

#define GLOAD_LDS16(gp, lp) __builtin_amdgcn_global_load_lds( \
    (const __attribute__((address_space(1))) void*)(gp), \
    (__attribute__((address_space(3))) void*)(lp), 16, 0, 0)

__device__ __forceinline__ unsigned short f2bf_rne(float f) {
    unsigned int u = __float_as_uint(f);
    unsigned int r = (u + 0x7FFFu + ((u >> 16) & 1u)) >> 16;
    return (unsigned short)r;
}
__device__ __forceinline__ float bf2f(unsigned short h) {
    return __uint_as_float(((unsigned int)h) << 16);
}

// ---------------- split fp32 -> packed [hi(256) || lo(256)] bf16 -------------
__global__ void split_pack_kernel(const float* __restrict__ src,
                                  unsigned short* __restrict__ dst) {
    size_t i = ((size_t)blockIdx.x * blockDim.x + threadIdx.x) * 8;
    int row = (int)(i >> 8);
    int col = (int)(i & 255);
    float4 v0 = *reinterpret_cast<const float4*>(src + i);
    float4 v1 = *reinterpret_cast<const float4*>(src + i + 4);
    float f[8] = {v0.x, v0.y, v0.z, v0.w, v1.x, v1.y, v1.z, v1.w};
    u16x8 h, l;
    #pragma unroll
    for (int j = 0; j < 8; ++j) {
        unsigned short hb = f2bf_rne(f[j]);
        h[j] = hb;
        l[j] = f2bf_rne(f[j] - bf2f(hb));
    }
    *reinterpret_cast<u16x8*>(dst + (size_t)row * KV + col) = h;
    *reinterpret_cast<u16x8*>(dst + (size_t)row * KV + 256 + col) = l;
}

// ---------------- c_sq: one wave per code ----------------
__global__ void csq_kernel(const float* __restrict__ C, float* __restrict__ csq) {
    int gtid = blockIdx.x * blockDim.x + threadIdx.x;
    int wave = gtid >> 6;
    int lane = threadIdx.x & 63;
    float4 v = reinterpret_cast<const float4*>(C + (size_t)wave * DIM)[lane];
    float s = v.x * v.x + v.y * v.y + v.z * v.z + v.w * v.w;
    #pragma unroll
    for (int m = 32; m; m >>= 1) s += __shfl_xor(s, m);
    if (lane == 0) csq[wave] = s;
}

__global__ void init_kernel(int* count) { *count = 0; }

// K-offsets (shorts) into the packed [hi||lo] K=512 operands, BK=64:
// steps 0-3: hi.hi  4-7: hi(A).lo(B)  8-11: lo(A).hi(B)
__device__ __forceinline__ int AK0(int s) {
    return ((s >= 8) ? 256 : 0) + (s & 3) * 64;
}
__device__ __forceinline__ int BK0(int s) {
    return ((s >= 4 && s < 8) ? 256 : 0) + (s & 3) * 64;
}

// ---------------- phase 1: 256x256-tile, BK=64, 4-phase MFMA GEMM ------------
// grid 4096 = 128 rowblocks x 32 codeblocks, 512 thr = 8 waves (2M x 4N)
// LDS 128 KiB dynamic: A dbuf [2][16384] shorts @0, B dbuf @32768 shorts
__global__ __launch_bounds__(512, 2) void gemm_argmin_kernel(
        const unsigned short* __restrict__ A2,   // [32768][512]
        const unsigned short* __restrict__ B2,   // [8192][512]
        const float* __restrict__ csq,
        float4* __restrict__ partials) {         // [32 slots][32768 rows]
    extern __shared__ unsigned short S[];        // 131072 B

    const int tid  = threadIdx.x;
    const int w    = tid >> 6;
    const int l    = tid & 63;
    const int wrM  = w >> 2;        // 0..1  -> rows [wrM*128, +128)
    const int wcN  = w & 3;         // 0..3  -> codes [wcN*64, +64)
    const int lcol = l & 15;
    const int g    = l >> 4;

    // bijective XCD swizzle: 4096 wg, 512 per XCD; rb fast (B slice L2-resident)
    const int swz = (blockIdx.x & 7) * 512 + (blockIdx.x >> 3);
    const int rb  = swz & 127;
    const int cbI = swz >> 7;
    const int rowbase  = rb * 256;
    const int codebase = cbI * 256;

    // staging: chunk = 1 KB = 8 rows x 128 B. Wave w stages A chunks 4w..4w+3
    // and B chunks 4w..4w+3. LDS dest is linear (base + lane*16 by HW);
    // global source fetches k-slot (l&7)^(l>>3) so reads can swizzle.
    const int stRowIn = l >> 3;                  // row within chunk (0..7)
    const int stSwz   = (l & 7) ^ stRowIn;       // swizzled 16B k-slot

    f32x4 acc[8][4];
    #pragma unroll
    for (int m = 0; m < 8; ++m)
        #pragma unroll
        for (int n = 0; n < 4; ++n) acc[m][n] = (f32x4){0.f, 0.f, 0.f, 0.f};

    // prologue: stage tile 0 into buf 0
    {
        const int ak = AK0(0), bk = BK0(0);
        #pragma unroll
        for (int i = 0; i < 4; ++i) {
            const int c = 4 * w + i;
            GLOAD_LDS16(A2 + (size_t)(rowbase + c * 8 + stRowIn) * KV + ak + stSwz * 8,
                        &S[c * 512]);
            GLOAD_LDS16(B2 + (size_t)(codebase + c * 8 + stRowIn) * KV + bk + stSwz * 8,
                        &S[32768 + c * 512]);
        }
    }

    #pragma unroll 1
    for (int s = 0; s < NSTEP; ++s) {
        const int cur = s & 1;
        const int nxt = cur ^ 1;
        int sn = s + 1; if (sn == NSTEP) sn = 0;   // wrap: harmless dead stage
        const int ak = AK0(sn), bk = BK0(sn);
        #pragma unroll
        for (int i = 0; i < 4; ++i) {
            const int c = 4 * w + i;
            GLOAD_LDS16(A2 + (size_t)(rowbase + c * 8 + stRowIn) * KV + ak + stSwz * 8,
                        &S[nxt * 16384 + c * 512]);
            GLOAD_LDS16(B2 + (size_t)(codebase + c * 8 + stRowIn) * KV + bk + stSwz * 8,
                        &S[32768 + nxt * 16384 + c * 512]);
        }
        // wait only for the PREVIOUS tile's 8 loads (aged one full step);
        // barrier makes every wave's retirement visible block-wide.
        asm volatile("s_waitcnt vmcnt(8)" ::: "memory");
        __builtin_amdgcn_s_barrier();
        __builtin_amdgcn_sched_barrier(0);

        const unsigned short* Ab = &S[cur * 16384];
        const unsigned short* Bb = &S[32768 + cur * 16384];

        // ---- 4 phases: (kh, m-half). Each: reads -> barrier -> lgkm(0) ->
        //      setprio(1) -> 16 MFMA -> setprio(0) -> barrier.
        #pragma unroll
        for (int kh = 0; kh < 2; ++kh) {
            const int slot = ((kh << 2) | g) ^ (lcol & 7);
            bf16x8 b0, b1, b2, b3;                 // live across both h-phases
            #pragma unroll
            for (int h = 0; h < 2; ++h) {
                bf16x8 a0, a1, a2, a3;
                {
                    const int r0 = wrM * 128 + (h * 4 + 0) * 16 + lcol;
                    a0 = *reinterpret_cast<const bf16x8*>(&Ab[(r0 + 0 ) * 64 + slot * 8]);
                    a1 = *reinterpret_cast<const bf16x8*>(&Ab[(r0 + 16) * 64 + slot * 8]);
                    a2 = *reinterpret_cast<const bf16x8*>(&Ab[(r0 + 32) * 64 + slot * 8]);
                    a3 = *reinterpret_cast<const bf16x8*>(&Ab[(r0 + 48) * 64 + slot * 8]);
                }
                if (h == 0) {
                    const int rb0 = wcN * 64 + lcol;
                    b0 = *reinterpret_cast<const bf16x8*>(&Bb[(rb0 + 0 ) * 64 + slot * 8]);
                    b1 = *reinterpret_cast<const bf16x8*>(&Bb[(rb0 + 16) * 64 + slot * 8]);
                    b2 = *reinterpret_cast<const bf16x8*>(&Bb[(rb0 + 32) * 64 + slot * 8]);
                    b3 = *reinterpret_cast<const bf16x8*>(&Bb[(rb0 + 48) * 64 + slot * 8]);
                }
                __builtin_amdgcn_s_barrier();
                asm volatile("s_waitcnt lgkmcnt(0)" ::: "memory");
                __builtin_amdgcn_sched_barrier(0);
                __builtin_amdgcn_s_setprio(1);
                #pragma unroll
                for (int mm = 0; mm < 4; ++mm) {
                    const int m = h * 4 + mm;
                    const bf16x8 am = (mm == 0) ? a0 : (mm == 1) ? a1 : (mm == 2) ? a2 : a3;
                    acc[m][0] = __builtin_amdgcn_mfma_f32_16x16x32_bf16(am, b0, acc[m][0], 0, 0, 0);
                    acc[m][1] = __builtin_amdgcn_mfma_f32_16x16x32_bf16(am, b1, acc[m][1], 0, 0, 0);
                    acc[m][2] = __builtin_amdgcn_mfma_f32_16x16x32_bf16(am, b2, acc[m][2], 0, 0, 0);
                    acc[m][3] = __builtin_amdgcn_mfma_f32_16x16x32_bf16(am, b3, acc[m][3], 0, 0, 0);
                }
                __builtin_amdgcn_s_setprio(0);
                __builtin_amdgcn_sched_barrier(0);
                __builtin_amdgcn_s_barrier();
            }
        }
    }

    // drain the wrap-staged loads before reusing LDS
    asm volatile("s_waitcnt vmcnt(0)" ::: "memory");
    __builtin_amdgcn_s_barrier();
    asm volatile("" ::: "memory");

    // ---- epilogue: dist = csq - 2*dot, top-2, fold across 4 N-waves in LDS
    float4* T = reinterpret_cast<float4*>(S);    // [256 rows][4 wc]
    #pragma unroll
    for (int m = 0; m < 8; ++m) {
        #pragma unroll
        for (int r = 0; r < 4; ++r) {
            float v1 = 3.4e38f, v2 = 3.4e38f; int i1 = 0x7fffffff;
            #pragma unroll
            for (int n = 0; n < 4; ++n) {
                int code = codebase + wcN * 64 + n * 16 + lcol;
                float d = fmaf(-2.0f, acc[m][n][r], csq[code]);
                float vmax = fmaxf(d, v1);
                v2 = fminf(v2, vmax);
                bool lt = d < v1;
                v1 = lt ? d : v1;
                i1 = lt ? code : i1;
            }
            #pragma unroll
            for (int mask = 1; mask < 16; mask <<= 1) {
                float ov1 = __shfl_xor(v1, mask);
                float ov2 = __shfl_xor(v2, mask);
                int   oi1 = __shfl_xor(i1, mask);
                float nv2 = fminf(fminf(v2, ov2), fmaxf(v1, ov1));
                bool take = (ov1 < v1) || (ov1 == v1 && oi1 < i1);
                v1 = take ? ov1 : v1;
                i1 = take ? oi1 : i1;
                v2 = nv2;
            }
            if (lcol == ((m * 4 + r) & 15)) {
                int rowL = wrM * 128 + m * 16 + g * 4 + r;
                T[rowL * 4 + wcN] = make_float4(v1, v2, __int_as_float(i1), 0.f);
            }
        }
    }
    __syncthreads();
    if (tid < 256) {
        float v1 = 3.4e38f, v2 = 3.4e38f; int i1 = 0x7fffffff;
        #pragma unroll
        for (int s2 = 0; s2 < 4; ++s2) {
            float4 p = T[tid * 4 + s2];
            int pi = __float_as_int(p.z);
            float nv2 = fminf(fminf(v2, p.y), fmaxf(v1, p.x));
            bool take = (p.x < v1) || (p.x == v1 && pi < i1);
            i1 = take ? pi : i1;
            v1 = fminf(v1, p.x);
            v2 = nv2;
        }
        partials[(size_t)cbI * N_ROWS + rowbase + tid] =
            make_float4(v1, v2, __int_as_float(i1), 0.f);
    }
}

// ---------------- reduce 32 slot-major partials per row -> idx or flag -------
__global__ void reduce_kernel(const float4* __restrict__ partials,
                              int* __restrict__ idx,
                              int* __restrict__ flaglist, int* __restrict__ count) {
    int row = blockIdx.x * 256 + threadIdx.x;
    float v1 = 3.4e38f, v2 = 3.4e38f; int i1 = 0x7fffffff;
    #pragma unroll
    for (int s = 0; s < 32; ++s) {
        float4 p = partials[(size_t)s * N_ROWS + row];
        int pi = __float_as_int(p.z);
        float nv2 = fminf(fminf(v2, p.y), fmaxf(v1, p.x));
        bool take = (p.x < v1) || (p.x == v1 && pi < i1);
        i1 = take ? pi : i1;
        v1 = fminf(v1, p.x);
        v2 = nv2;
    }
    if (v2 - v1 > TWO_EPS) {
        idx[row] = i1;
    } else {
        int p = atomicAdd(count, 1);
        flaglist[p] = row;
    }
}

// ---------------- exact fp32 recheck: one BLOCK per flagged row --------------
__global__ __launch_bounds__(256) void recheck_kernel(
        const float* __restrict__ X, const float* __restrict__ C,
        const float* __restrict__ csq, const int* __restrict__ flaglist,
        const int* __restrict__ count, int* __restrict__ idx) {
    __shared__ __align__(16) float xs[DIM];
    __shared__ float rv[4];
    __shared__ int   ri[4];
    const int nf = *count;
    const int tid = threadIdx.x;

    for (int b = blockIdx.x; b < nf; b += gridDim.x) {
        const int row = flaglist[b];
        __syncthreads();
        if (tid < 64)
            reinterpret_cast<float4*>(xs)[tid] =
                reinterpret_cast<const float4*>(X + (size_t)row * DIM)[tid];
        __syncthreads();

        float best = 3.4e38f; int bi = 0x7fffffff;
        for (int j = 0; j < 32; j += 2) {
            const int c0 = tid + j * 256;
            const int c1 = c0 + 256;
            const float* p0 = C + (size_t)c0 * DIM;
            const float* p1 = C + (size_t)c1 * DIM;
            float d0 = 0.f, d1 = 0.f;
            #pragma unroll 8
            for (int d = 0; d < DIM; d += 4) {
                float4 a  = *reinterpret_cast<const float4*>(xs + d);
                float4 q0 = *reinterpret_cast<const float4*>(p0 + d);
                float4 q1 = *reinterpret_cast<const float4*>(p1 + d);
                d0 = fmaf(a.x, q0.x, d0); d0 = fmaf(a.y, q0.y, d0);
                d0 = fmaf(a.z, q0.z, d0); d0 = fmaf(a.w, q0.w, d0);
                d1 = fmaf(a.x, q1.x, d1); d1 = fmaf(a.y, q1.y, d1);
                d1 = fmaf(a.z, q1.z, d1); d1 = fmaf(a.w, q1.w, d1);
            }
            float dist0 = fmaf(-2.f, d0, csq[c0]);
            float dist1 = fmaf(-2.f, d1, csq[c1]);
            if (dist0 < best) { best = dist0; bi = c0; }
            if (dist1 < best) { best = dist1; bi = c1; }
        }
        #pragma unroll
        for (int m = 1; m < 64; m <<= 1) {
            float ov = __shfl_xor(best, m);
            int   oi = __shfl_xor(bi, m);
            if (ov < best || (ov == best && oi < bi)) { best = ov; bi = oi; }
        }
        if ((tid & 63) == 0) { rv[tid >> 6] = best; ri[tid >> 6] = bi; }
        __syncthreads();
        if (tid == 0) {
            #pragma unroll
            for (int wv = 1; wv < 4; ++wv) {
                if (rv[wv] < best || (rv[wv] == best && ri[wv] < bi)) {
                    best = rv[wv]; bi = ri[wv];
                }
            }
            idx[row] = bi;
        }
    }
}

// ---------------- gather: one wave per row, write both halves ----------------
__global__ void gather_kernel(const float* __restrict__ C,
                              const int* __restrict__ idx,
                              float* __restrict__ out) {
    const size_t half = (size_t)N_ROWS * DIM;
    int gtid = blockIdx.x * blockDim.x + threadIdx.x;
    int lane = threadIdx.x & 63;
    int wave = gtid >> 6;
    int nwaves = (gridDim.x * blockDim.x) >> 6;
    for (int row = wave; row < N_ROWS; row += nwaves) {
        int id = idx[row];
        float4 v = reinterpret_cast<const float4*>(C + (size_t)id * DIM)[lane];
        reinterpret_cast<float4*>(out + (size_t)row * DIM)[lane] = v;
        reinterpret_cast<float4*>(out + half + (size_t)row * DIM)[lane] = v;
    }
}

extern "C" void kernel_launch(void* const* d_in, const int* in_sizes, int n_in,
                              void* d_out, int out_size, void* d_ws, size_t ws_size,
                              hipStream_t stream) {
    const float* z  = (const float*)d_in[0];   // (32,1024,256) fp32
    const float* cb = (const float*)d_in[1];   // (8192,256)    fp32
    float* out = (float*)d_out;

    // big scratch in d_out (fully overwritten by gather at the end):
    char* sc = (char*)d_out;
    unsigned short* A2 = (unsigned short*)(sc);               // 33,554,432 B
    unsigned short* B2 = (unsigned short*)(sc + 33554432);    //  8,388,608 B
    float4* partials   = (float4*)(sc + 41943040);            // 16,777,216 B

    // small scratch in d_ws (~295 KB):
    float* csq    = (float*)d_ws;                              // 32 KB
    int*   idx    = (int*)((char*)d_ws + 32768);               // 128 KB
    int*   flags  = (int*)((char*)d_ws + 163840);              // 128 KB
    int*   count  = (int*)((char*)d_ws + 294912);              // 4 B

    static bool attr_done = false;
    if (!attr_done) {
        hipFuncSetAttribute((const void*)gemm_argmin_kernel,
                            hipFuncAttributeMaxDynamicSharedMemorySize, 131072);
        attr_done = true;
    }

    init_kernel<<<1, 1, 0, stream>>>(count);
    split_pack_kernel<<<(N_ROWS * DIM) / (256 * 8), 256, 0, stream>>>(z, A2);
    split_pack_kernel<<<(N_CODES * DIM) / (256 * 8), 256, 0, stream>>>(cb, B2);
    csq_kernel<<<(N_CODES * 64) / 256, 256, 0, stream>>>(cb, csq);
    gemm_argmin_kernel<<<4096, 512, 131072, stream>>>(A2, B2, csq, partials);
    reduce_kernel<<<N_ROWS / 256, 256, 0, stream>>>(partials, idx, flags, count);
    recheck_kernel<<<512, 256, 0, stream>>>(z, cb, csq, flags, count, idx);
    gather_kernel<<<2048, 256, 0, stream>>>(cb, idx, out);
}

// Round 7
// 842.880 us; speedup vs baseline: 1.0183x; 1.0183x over previous
//
#include <hip/hip_runtime.h>

#define N_ROWS 32768   // BS*SEQ
#define N_CODES 8192
#define DIM 256
#define KV 512         // packed K per operand (hi || lo)
#define NSTEP 24       // virtual K = 768, BK = 32
#define TWO_EPS 4e-6f  // > 2x sup error bound (~1.5e-6) of bf16-split distance

typedef __attribute__((ext_vector_type(8))) short bf16x8;
typedef __attribute__((ext_vector_type(4))) float f32x4;
typedef __attribute__((ext_vector_type(8))) unsigned short u16x8;

#define GLOAD_LDS16(gp, lp) __builtin_amdgcn_global_load_lds( \
    (const __attribute__((address_space(1))) void*)(gp), \
    (__attribute__((address_space(3))) void*)(lp), 16, 0, 0)

__device__ __forceinline__ unsigned short f2bf_rne(float f) {
    unsigned int u = __float_as_uint(f);
    unsigned int r = (u + 0x7FFFu + ((u >> 16) & 1u)) >> 16;
    return (unsigned short)r;
}
__device__ __forceinline__ float bf2f(unsigned short h) {
    return __uint_as_float(((unsigned int)h) << 16);
}

// ---------------- split fp32 -> packed [hi(256) || lo(256)] bf16 -------------
__global__ void split_pack_kernel(const float* __restrict__ src,
                                  unsigned short* __restrict__ dst) {
    size_t i = ((size_t)blockIdx.x * blockDim.x + threadIdx.x) * 8;
    int row = (int)(i >> 8);
    int col = (int)(i & 255);
    float4 v0 = *reinterpret_cast<const float4*>(src + i);
    float4 v1 = *reinterpret_cast<const float4*>(src + i + 4);
    float f[8] = {v0.x, v0.y, v0.z, v0.w, v1.x, v1.y, v1.z, v1.w};
    u16x8 h, l;
    #pragma unroll
    for (int j = 0; j < 8; ++j) {
        unsigned short hb = f2bf_rne(f[j]);
        h[j] = hb;
        l[j] = f2bf_rne(f[j] - bf2f(hb));
    }
    *reinterpret_cast<u16x8*>(dst + (size_t)row * KV + col) = h;
    *reinterpret_cast<u16x8*>(dst + (size_t)row * KV + 256 + col) = l;
}

// ---------------- c_sq: one wave per code ----------------
__global__ void csq_kernel(const float* __restrict__ C, float* __restrict__ csq) {
    int gtid = blockIdx.x * blockDim.x + threadIdx.x;
    int wave = gtid >> 6;
    int lane = threadIdx.x & 63;
    float4 v = reinterpret_cast<const float4*>(C + (size_t)wave * DIM)[lane];
    float s = v.x * v.x + v.y * v.y + v.z * v.z + v.w * v.w;
    #pragma unroll
    for (int m = 32; m; m >>= 1) s += __shfl_xor(s, m);
    if (lane == 0) csq[wave] = s;
}

__global__ void init_kernel(int* count) { *count = 0; }

// K-offsets (shorts) into packed [hi||lo] K=512 operands, BK=32:
// steps 0-7: hi.hi  8-15: hi(A).lo(B)  16-23: lo(A).hi(B)
__device__ __forceinline__ int AK0(int s) {
    return ((s >= 16) ? 256 : 0) + (s & 7) * 32;
}
__device__ __forceinline__ int BK0(int s) {
    return ((s >= 8 && s < 16) ? 256 : 0) + (s & 7) * 32;
}

// ---------------- phase 1: 256x256 tile, BK=32 ring-4, 2-phase/step ----------
// grid 4096 = 128 rowblocks x 32 codeblocks, 512 thr = 8 waves (2M x 4N)
// LDS 128 KiB: A slots [4][8192] shorts @0, B slots @32768 shorts.
// Per phase: 4-8 ds_read_b128 + 2 global_load_lds (step s+3) + 16-MFMA cluster.
// vmcnt(8) once per step: retires step s+1's loads (issued 6 phases earlier).
__global__ __launch_bounds__(512, 2) void gemm_argmin_kernel(
        const unsigned short* __restrict__ A2,   // [32768][512]
        const unsigned short* __restrict__ B2,   // [8192][512]
        const float* __restrict__ csq,
        float4* __restrict__ partials) {         // [32 slots][32768 rows]
    extern __shared__ unsigned short S[];        // 131072 B

    const int tid  = threadIdx.x;
    const int w    = tid >> 6;
    const int l    = tid & 63;
    const int wrM  = w >> 2;        // 0..1  -> rows [wrM*128, +128)
    const int wcN  = w & 3;         // 0..3  -> codes [wcN*64, +64)
    const int lcol = l & 15;
    const int g    = l >> 4;

    // bijective XCD swizzle: 4096 wg, 512 per XCD; rb fast (B slice L2-resident)
    const int swz = (blockIdx.x & 7) * 512 + (blockIdx.x >> 3);
    const int rb  = swz & 127;
    const int cbI = swz >> 7;
    const int rowbase  = rb * 256;
    const int codebase = cbI * 256;

    // staging: chunk = 1 KB = 16 rows x 32 k (64 B/row). Wave w owns chunks
    // 2w, 2w+1 (of 16) per operand per step. Lane l writes linear cell
    // (row_in = l>>2, cslot = l&3); fetch global slot (l&3)^(row_in&3) so the
    // LDS holds the XOR-swizzled layout (rule 21: swizzle source + read).
    const int stRowIn = l >> 2;                         // 0..15
    const int stCol   = (((l & 3) ^ (stRowIn & 3)) * 8);

    f32x4 acc[8][4];
    #pragma unroll
    for (int m = 0; m < 8; ++m)
        #pragma unroll
        for (int n = 0; n < 4; ++n) acc[m][n] = (f32x4){0.f, 0.f, 0.f, 0.f};

    // prologue: stage steps 0,1,2 into slots 0,1,2
    #pragma unroll
    for (int s0 = 0; s0 < 3; ++s0) {
        const int ak = AK0(s0), bk = BK0(s0);
        #pragma unroll
        for (int i = 0; i < 2; ++i) {
            const int c = 2 * w + i;
            GLOAD_LDS16(A2 + (size_t)(rowbase + c * 16 + stRowIn) * KV + ak + stCol,
                        &S[s0 * 8192 + c * 512]);
            GLOAD_LDS16(B2 + (size_t)(codebase + c * 16 + stRowIn) * KV + bk + stCol,
                        &S[32768 + s0 * 8192 + c * 512]);
        }
    }
    // retire step 0 (4 oldest of 12); publish
    asm volatile("s_waitcnt vmcnt(8)" ::: "memory");
    __builtin_amdgcn_sched_barrier(0);
    __builtin_amdgcn_s_barrier();

    const int rslot = g ^ (lcol & 3);                   // swizzled 8-short slot

    #pragma unroll 1
    for (int so = 0; so < NSTEP; so += 4) {
        #pragma unroll
        for (int k = 0; k < 4; ++k) {
            const int s = so + k;
            const unsigned short* Ab = &S[k * 8192];
            const unsigned short* Bb = &S[32768 + k * 8192];
            int sn = s + 3; if (sn >= NSTEP) sn -= NSTEP;  // wrap: dead stage
            const int snk = (k + 3) & 3;
            const int ak = AK0(sn), bk = BK0(sn);

            // ================= phase 0: m 0-3, read b0-3, stage A(s+3) ======
            bf16x8 a0, a1, a2, a3, b0, b1, b2, b3;
            {
                const int r0 = wrM * 128 + lcol;
                a0 = *reinterpret_cast<const bf16x8*>(&Ab[(r0 + 0 ) * 32 + rslot * 8]);
                a1 = *reinterpret_cast<const bf16x8*>(&Ab[(r0 + 16) * 32 + rslot * 8]);
                a2 = *reinterpret_cast<const bf16x8*>(&Ab[(r0 + 32) * 32 + rslot * 8]);
                a3 = *reinterpret_cast<const bf16x8*>(&Ab[(r0 + 48) * 32 + rslot * 8]);
                const int rbq = wcN * 64 + lcol;
                b0 = *reinterpret_cast<const bf16x8*>(&Bb[(rbq + 0 ) * 32 + rslot * 8]);
                b1 = *reinterpret_cast<const bf16x8*>(&Bb[(rbq + 16) * 32 + rslot * 8]);
                b2 = *reinterpret_cast<const bf16x8*>(&Bb[(rbq + 32) * 32 + rslot * 8]);
                b3 = *reinterpret_cast<const bf16x8*>(&Bb[(rbq + 48) * 32 + rslot * 8]);
            }
            #pragma unroll
            for (int i = 0; i < 2; ++i) {
                const int c = 2 * w + i;
                GLOAD_LDS16(A2 + (size_t)(rowbase + c * 16 + stRowIn) * KV + ak + stCol,
                            &S[snk * 8192 + c * 512]);
            }
            __builtin_amdgcn_s_barrier();
            asm volatile("s_waitcnt lgkmcnt(0)" ::: "memory");
            __builtin_amdgcn_sched_barrier(0);
            __builtin_amdgcn_s_setprio(1);
            acc[0][0] = __builtin_amdgcn_mfma_f32_16x16x32_bf16(a0, b0, acc[0][0], 0, 0, 0);
            acc[0][1] = __builtin_amdgcn_mfma_f32_16x16x32_bf16(a0, b1, acc[0][1], 0, 0, 0);
            acc[0][2] = __builtin_amdgcn_mfma_f32_16x16x32_bf16(a0, b2, acc[0][2], 0, 0, 0);
            acc[0][3] = __builtin_amdgcn_mfma_f32_16x16x32_bf16(a0, b3, acc[0][3], 0, 0, 0);
            acc[1][0] = __builtin_amdgcn_mfma_f32_16x16x32_bf16(a1, b0, acc[1][0], 0, 0, 0);
            acc[1][1] = __builtin_amdgcn_mfma_f32_16x16x32_bf16(a1, b1, acc[1][1], 0, 0, 0);
            acc[1][2] = __builtin_amdgcn_mfma_f32_16x16x32_bf16(a1, b2, acc[1][2], 0, 0, 0);
            acc[1][3] = __builtin_amdgcn_mfma_f32_16x16x32_bf16(a1, b3, acc[1][3], 0, 0, 0);
            acc[2][0] = __builtin_amdgcn_mfma_f32_16x16x32_bf16(a2, b0, acc[2][0], 0, 0, 0);
            acc[2][1] = __builtin_amdgcn_mfma_f32_16x16x32_bf16(a2, b1, acc[2][1], 0, 0, 0);
            acc[2][2] = __builtin_amdgcn_mfma_f32_16x16x32_bf16(a2, b2, acc[2][2], 0, 0, 0);
            acc[2][3] = __builtin_amdgcn_mfma_f32_16x16x32_bf16(a2, b3, acc[2][3], 0, 0, 0);
            acc[3][0] = __builtin_amdgcn_mfma_f32_16x16x32_bf16(a3, b0, acc[3][0], 0, 0, 0);
            acc[3][1] = __builtin_amdgcn_mfma_f32_16x16x32_bf16(a3, b1, acc[3][1], 0, 0, 0);
            acc[3][2] = __builtin_amdgcn_mfma_f32_16x16x32_bf16(a3, b2, acc[3][2], 0, 0, 0);
            acc[3][3] = __builtin_amdgcn_mfma_f32_16x16x32_bf16(a3, b3, acc[3][3], 0, 0, 0);
            __builtin_amdgcn_s_setprio(0);
            __builtin_amdgcn_s_barrier();

            // ================= phase 1: m 4-7 (reuse b), stage B(s+3) =======
            {
                const int r0 = wrM * 128 + 64 + lcol;
                a0 = *reinterpret_cast<const bf16x8*>(&Ab[(r0 + 0 ) * 32 + rslot * 8]);
                a1 = *reinterpret_cast<const bf16x8*>(&Ab[(r0 + 16) * 32 + rslot * 8]);
                a2 = *reinterpret_cast<const bf16x8*>(&Ab[(r0 + 32) * 32 + rslot * 8]);
                a3 = *reinterpret_cast<const bf16x8*>(&Ab[(r0 + 48) * 32 + rslot * 8]);
            }
            #pragma unroll
            for (int i = 0; i < 2; ++i) {
                const int c = 2 * w + i;
                GLOAD_LDS16(B2 + (size_t)(codebase + c * 16 + stRowIn) * KV + bk + stCol,
                            &S[32768 + snk * 8192 + c * 512]);
            }
            __builtin_amdgcn_s_barrier();
            asm volatile("s_waitcnt lgkmcnt(0)" ::: "memory");
            __builtin_amdgcn_sched_barrier(0);
            __builtin_amdgcn_s_setprio(1);
            acc[4][0] = __builtin_amdgcn_mfma_f32_16x16x32_bf16(a0, b0, acc[4][0], 0, 0, 0);
            acc[4][1] = __builtin_amdgcn_mfma_f32_16x16x32_bf16(a0, b1, acc[4][1], 0, 0, 0);
            acc[4][2] = __builtin_amdgcn_mfma_f32_16x16x32_bf16(a0, b2, acc[4][2], 0, 0, 0);
            acc[4][3] = __builtin_amdgcn_mfma_f32_16x16x32_bf16(a0, b3, acc[4][3], 0, 0, 0);
            acc[5][0] = __builtin_amdgcn_mfma_f32_16x16x32_bf16(a1, b0, acc[5][0], 0, 0, 0);
            acc[5][1] = __builtin_amdgcn_mfma_f32_16x16x32_bf16(a1, b1, acc[5][1], 0, 0, 0);
            acc[5][2] = __builtin_amdgcn_mfma_f32_16x16x32_bf16(a1, b2, acc[5][2], 0, 0, 0);
            acc[5][3] = __builtin_amdgcn_mfma_f32_16x16x32_bf16(a1, b3, acc[5][3], 0, 0, 0);
            acc[6][0] = __builtin_amdgcn_mfma_f32_16x16x32_bf16(a2, b0, acc[6][0], 0, 0, 0);
            acc[6][1] = __builtin_amdgcn_mfma_f32_16x16x32_bf16(a2, b1, acc[6][1], 0, 0, 0);
            acc[6][2] = __builtin_amdgcn_mfma_f32_16x16x32_bf16(a2, b2, acc[6][2], 0, 0, 0);
            acc[6][3] = __builtin_amdgcn_mfma_f32_16x16x32_bf16(a2, b3, acc[6][3], 0, 0, 0);
            acc[7][0] = __builtin_amdgcn_mfma_f32_16x16x32_bf16(a3, b0, acc[7][0], 0, 0, 0);
            acc[7][1] = __builtin_amdgcn_mfma_f32_16x16x32_bf16(a3, b1, acc[7][1], 0, 0, 0);
            acc[7][2] = __builtin_amdgcn_mfma_f32_16x16x32_bf16(a3, b2, acc[7][2], 0, 0, 0);
            acc[7][3] = __builtin_amdgcn_mfma_f32_16x16x32_bf16(a3, b3, acc[7][3], 0, 0, 0);
            __builtin_amdgcn_s_setprio(0);
            // retire step s+1's 4 loads (issued 6 phases ago -> no stall);
            // keep s+2/s+3's 8 in flight. Barrier publishes block-wide.
            asm volatile("s_waitcnt vmcnt(8)" ::: "memory");
            __builtin_amdgcn_sched_barrier(0);
            __builtin_amdgcn_s_barrier();
        }
    }

    // drain the dead wrap stages before reusing LDS
    asm volatile("s_waitcnt vmcnt(0)" ::: "memory");
    __builtin_amdgcn_s_barrier();
    asm volatile("" ::: "memory");

    // ---- epilogue: dist = csq - 2*dot, top-2, fold across 4 N-waves in LDS
    float4* T = reinterpret_cast<float4*>(S);    // [256 rows][4 wc]
    #pragma unroll
    for (int m = 0; m < 8; ++m) {
        #pragma unroll
        for (int r = 0; r < 4; ++r) {
            float v1 = 3.4e38f, v2 = 3.4e38f; int i1 = 0x7fffffff;
            #pragma unroll
            for (int n = 0; n < 4; ++n) {
                int code = codebase + wcN * 64 + n * 16 + lcol;
                float d = fmaf(-2.0f, acc[m][n][r], csq[code]);
                float vmax = fmaxf(d, v1);
                v2 = fminf(v2, vmax);
                bool lt = d < v1;
                v1 = lt ? d : v1;
                i1 = lt ? code : i1;
            }
            #pragma unroll
            for (int mask = 1; mask < 16; mask <<= 1) {
                float ov1 = __shfl_xor(v1, mask);
                float ov2 = __shfl_xor(v2, mask);
                int   oi1 = __shfl_xor(i1, mask);
                float nv2 = fminf(fminf(v2, ov2), fmaxf(v1, ov1));
                bool take = (ov1 < v1) || (ov1 == v1 && oi1 < i1);
                v1 = take ? ov1 : v1;
                i1 = take ? oi1 : i1;
                v2 = nv2;
            }
            if (lcol == ((m * 4 + r) & 15)) {
                int rowL = wrM * 128 + m * 16 + g * 4 + r;
                T[rowL * 4 + wcN] = make_float4(v1, v2, __int_as_float(i1), 0.f);
            }
        }
    }
    __syncthreads();
    if (tid < 256) {
        float v1 = 3.4e38f, v2 = 3.4e38f; int i1 = 0x7fffffff;
        #pragma unroll
        for (int s2 = 0; s2 < 4; ++s2) {
            float4 p = T[tid * 4 + s2];
            int pi = __float_as_int(p.z);
            float nv2 = fminf(fminf(v2, p.y), fmaxf(v1, p.x));
            bool take = (p.x < v1) || (p.x == v1 && pi < i1);
            i1 = take ? pi : i1;
            v1 = fminf(v1, p.x);
            v2 = nv2;
        }
        partials[(size_t)cbI * N_ROWS + rowbase + tid] =
            make_float4(v1, v2, __int_as_float(i1), 0.f);
    }
}

// ---------------- reduce 32 slot-major partials per row -> idx or flag -------
__global__ void reduce_kernel(const float4* __restrict__ partials,
                              int* __restrict__ idx,
                              int* __restrict__ flaglist, int* __restrict__ count) {
    int row = blockIdx.x * 256 + threadIdx.x;
    float v1 = 3.4e38f, v2 = 3.4e38f; int i1 = 0x7fffffff;
    #pragma unroll
    for (int s = 0; s < 32; ++s) {
        float4 p = partials[(size_t)s * N_ROWS + row];
        int pi = __float_as_int(p.z);
        float nv2 = fminf(fminf(v2, p.y), fmaxf(v1, p.x));
        bool take = (p.x < v1) || (p.x == v1 && pi < i1);
        i1 = take ? pi : i1;
        v1 = fminf(v1, p.x);
        v2 = nv2;
    }
    if (v2 - v1 > TWO_EPS) {
        idx[row] = i1;
    } else {
        int p = atomicAdd(count, 1);
        flaglist[p] = row;
    }
}

// ---------------- exact fp32 recheck: one BLOCK per flagged row --------------
__global__ __launch_bounds__(256) void recheck_kernel(
        const float* __restrict__ X, const float* __restrict__ C,
        const float* __restrict__ csq, const int* __restrict__ flaglist,
        const int* __restrict__ count, int* __restrict__ idx) {
    __shared__ __align__(16) float xs[DIM];
    __shared__ float rv[4];
    __shared__ int   ri[4];
    const int nf = *count;
    const int tid = threadIdx.x;

    for (int b = blockIdx.x; b < nf; b += gridDim.x) {
        const int row = flaglist[b];
        __syncthreads();
        if (tid < 64)
            reinterpret_cast<float4*>(xs)[tid] =
                reinterpret_cast<const float4*>(X + (size_t)row * DIM)[tid];
        __syncthreads();

        float best = 3.4e38f; int bi = 0x7fffffff;
        for (int j = 0; j < 32; j += 2) {
            const int c0 = tid + j * 256;
            const int c1 = c0 + 256;
            const float* p0 = C + (size_t)c0 * DIM;
            const float* p1 = C + (size_t)c1 * DIM;
            float d0 = 0.f, d1 = 0.f;
            #pragma unroll 8
            for (int d = 0; d < DIM; d += 4) {
                float4 a  = *reinterpret_cast<const float4*>(xs + d);
                float4 q0 = *reinterpret_cast<const float4*>(p0 + d);
                float4 q1 = *reinterpret_cast<const float4*>(p1 + d);
                d0 = fmaf(a.x, q0.x, d0); d0 = fmaf(a.y, q0.y, d0);
                d0 = fmaf(a.z, q0.z, d0); d0 = fmaf(a.w, q0.w, d0);
                d1 = fmaf(a.x, q1.x, d1); d1 = fmaf(a.y, q1.y, d1);
                d1 = fmaf(a.z, q1.z, d1); d1 = fmaf(a.w, q1.w, d1);
            }
            float dist0 = fmaf(-2.f, d0, csq[c0]);
            float dist1 = fmaf(-2.f, d1, csq[c1]);
            if (dist0 < best) { best = dist0; bi = c0; }
            if (dist1 < best) { best = dist1; bi = c1; }
        }
        #pragma unroll
        for (int m = 1; m < 64; m <<= 1) {
            float ov = __shfl_xor(best, m);
            int   oi = __shfl_xor(bi, m);
            if (ov < best || (ov == best && oi < bi)) { best = ov; bi = oi; }
        }
        if ((tid & 63) == 0) { rv[tid >> 6] = best; ri[tid >> 6] = bi; }
        __syncthreads();
        if (tid == 0) {
            #pragma unroll
            for (int wv = 1; wv < 4; ++wv) {
                if (rv[wv] < best || (rv[wv] == best && ri[wv] < bi)) {
                    best = rv[wv]; bi = ri[wv];
                }
            }
            idx[row] = bi;
        }
    }
}

// ---------------- gather: one wave per row, write both halves ----------------
__global__ void gather_kernel(const float* __restrict__ C,
                              const int* __restrict__ idx,
                              float* __restrict__ out) {
    const size_t half = (size_t)N_ROWS * DIM;
    int gtid = blockIdx.x * blockDim.x + threadIdx.x;
    int lane = threadIdx.x & 63;
    int wave = gtid >> 6;
    int nwaves = (gridDim.x * blockDim.x) >> 6;
    for (int row = wave; row < N_ROWS; row += nwaves) {
        int id = idx[row];
        float4 v = reinterpret_cast<const float4*>(C + (size_t)id * DIM)[lane];
        reinterpret_cast<float4*>(out + (size_t)row * DIM)[lane] = v;
        reinterpret_cast<float4*>(out + half + (size_t)row * DIM)[lane] = v;
    }
}

extern "C" void kernel_launch(void* const* d_in, const int* in_sizes, int n_in,
                              void* d_out, int out_size, void* d_ws, size_t ws_size,
                              hipStream_t stream) {
    const float* z  = (const float*)d_in[0];   // (32,1024,256) fp32
    const float* cb = (const float*)d_in[1];   // (8192,256)    fp32
    float* out = (float*)d_out;

    // big scratch in d_out (fully overwritten by gather at the end):
    char* sc = (char*)d_out;
    unsigned short* A2 = (unsigned short*)(sc);               // 33,554,432 B
    unsigned short* B2 = (unsigned short*)(sc + 33554432);    //  8,388,608 B
    float4* partials   = (float4*)(sc + 41943040);            // 16,777,216 B

    // small scratch in d_ws (~295 KB):
    float* csq    = (float*)d_ws;                              // 32 KB
    int*   idx    = (int*)((char*)d_ws + 32768);               // 128 KB
    int*   flags  = (int*)((char*)d_ws + 163840);              // 128 KB
    int*   count  = (int*)((char*)d_ws + 294912);              // 4 B

    static bool attr_done = false;
    if (!attr_done) {
        hipFuncSetAttribute((const void*)gemm_argmin_kernel,
                            hipFuncAttributeMaxDynamicSharedMemorySize, 131072);
        attr_done = true;
    }

    init_kernel<<<1, 1, 0, stream>>>(count);
    split_pack_kernel<<<(N_ROWS * DIM) / (256 * 8), 256, 0, stream>>>(z, A2);
    split_pack_kernel<<<(N_CODES * DIM) / (256 * 8), 256, 0, stream>>>(cb, B2);
    csq_kernel<<<(N_CODES * 64) / 256, 256, 0, stream>>>(cb, csq);
    gemm_argmin_kernel<<<4096, 512, 131072, stream>>>(A2, B2, csq, partials);
    reduce_kernel<<<N_ROWS / 256, 256, 0, stream>>>(partials, idx, flags, count);
    recheck_kernel<<<512, 256, 0, stream>>>(z, cb, csq, flags, count, idx);
    gather_kernel<<<2048, 256, 0, stream>>>(cb, idx, out);
}

// Round 8
// 805.533 us; speedup vs baseline: 1.0655x; 1.0464x over previous
//
#include <hip/hip_runtime.h>

#define N_ROWS 32768   // BS*SEQ
#define N_CODES 8192
#define DIM 256
#define KV 512         // packed K per operand (hi || lo)
#define NSTEP 24       // virtual K = 768, BK = 32
#define TWO_EPS 4e-6f  // > 2x sup error bound (~1.5e-6) of bf16-split distance

typedef __attribute__((ext_vector_type(8))) short bf16x8;
typedef __attribute__((ext_vector_type(4))) float f32x4;
typedef __attribute__((ext_vector_type(8))) unsigned short u16x8;

#define GLOAD_LDS16(gp, lp) __builtin_amdgcn_global_load_lds( \
    (const __attribute__((address_space(1))) void*)(gp), \
    (__attribute__((address_space(3))) void*)(lp), 16, 0, 0)

#define RD(base, off) (*reinterpret_cast<const bf16x8*>(&(base)[(off)]))

__device__ __forceinline__ unsigned short f2bf_rne(float f) {
    unsigned int u = __float_as_uint(f);
    unsigned int r = (u + 0x7FFFu + ((u >> 16) & 1u)) >> 16;
    return (unsigned short)r;
}
__device__ __forceinline__ float bf2f(unsigned short h) {
    return __uint_as_float(((unsigned int)h) << 16);
}

// ---------------- split fp32 -> packed [hi(256) || lo(256)] bf16 -------------
__global__ void split_pack_kernel(const float* __restrict__ src,
                                  unsigned short* __restrict__ dst) {
    size_t i = ((size_t)blockIdx.x * blockDim.x + threadIdx.x) * 8;
    int row = (int)(i >> 8);
    int col = (int)(i & 255);
    float4 v0 = *reinterpret_cast<const float4*>(src + i);
    float4 v1 = *reinterpret_cast<const float4*>(src + i + 4);
    float f[8] = {v0.x, v0.y, v0.z, v0.w, v1.x, v1.y, v1.z, v1.w};
    u16x8 h, l;
    #pragma unroll
    for (int j = 0; j < 8; ++j) {
        unsigned short hb = f2bf_rne(f[j]);
        h[j] = hb;
        l[j] = f2bf_rne(f[j] - bf2f(hb));
    }
    *reinterpret_cast<u16x8*>(dst + (size_t)row * KV + col) = h;
    *reinterpret_cast<u16x8*>(dst + (size_t)row * KV + 256 + col) = l;
}

// ---------------- c_sq: one wave per code ----------------
__global__ void csq_kernel(const float* __restrict__ C, float* __restrict__ csq) {
    int gtid = blockIdx.x * blockDim.x + threadIdx.x;
    int wave = gtid >> 6;
    int lane = threadIdx.x & 63;
    float4 v = reinterpret_cast<const float4*>(C + (size_t)wave * DIM)[lane];
    float s = v.x * v.x + v.y * v.y + v.z * v.z + v.w * v.w;
    #pragma unroll
    for (int m = 32; m; m >>= 1) s += __shfl_xor(s, m);
    if (lane == 0) csq[wave] = s;
}

__global__ void init_kernel(int* count) { *count = 0; }

// K-offsets (shorts) into packed [hi||lo] K=512 operands, BK=32:
// steps 0-7: hi.hi  8-15: hi(A).lo(B)  16-23: lo(A).hi(B)
__device__ __forceinline__ int AK0(int s) {
    return ((s >= 16) ? 256 : 0) + (s & 7) * 32;
}
__device__ __forceinline__ int BK0(int s) {
    return ((s >= 8 && s < 16) ? 256 : 0) + (s & 7) * 32;
}

// 16 MFMAs of one phase: acc[mb..mb+3][0..3]
#define MFMA16(mb, A0, A1, A2, A3, B0, B1, B2, B3)                                  \
    acc[mb+0][0] = __builtin_amdgcn_mfma_f32_16x16x32_bf16(A0, B0, acc[mb+0][0], 0, 0, 0); \
    acc[mb+0][1] = __builtin_amdgcn_mfma_f32_16x16x32_bf16(A0, B1, acc[mb+0][1], 0, 0, 0); \
    acc[mb+0][2] = __builtin_amdgcn_mfma_f32_16x16x32_bf16(A0, B2, acc[mb+0][2], 0, 0, 0); \
    acc[mb+0][3] = __builtin_amdgcn_mfma_f32_16x16x32_bf16(A0, B3, acc[mb+0][3], 0, 0, 0); \
    acc[mb+1][0] = __builtin_amdgcn_mfma_f32_16x16x32_bf16(A1, B0, acc[mb+1][0], 0, 0, 0); \
    acc[mb+1][1] = __builtin_amdgcn_mfma_f32_16x16x32_bf16(A1, B1, acc[mb+1][1], 0, 0, 0); \
    acc[mb+1][2] = __builtin_amdgcn_mfma_f32_16x16x32_bf16(A1, B2, acc[mb+1][2], 0, 0, 0); \
    acc[mb+1][3] = __builtin_amdgcn_mfma_f32_16x16x32_bf16(A1, B3, acc[mb+1][3], 0, 0, 0); \
    acc[mb+2][0] = __builtin_amdgcn_mfma_f32_16x16x32_bf16(A2, B0, acc[mb+2][0], 0, 0, 0); \
    acc[mb+2][1] = __builtin_amdgcn_mfma_f32_16x16x32_bf16(A2, B1, acc[mb+2][1], 0, 0, 0); \
    acc[mb+2][2] = __builtin_amdgcn_mfma_f32_16x16x32_bf16(A2, B2, acc[mb+2][2], 0, 0, 0); \
    acc[mb+2][3] = __builtin_amdgcn_mfma_f32_16x16x32_bf16(A2, B3, acc[mb+2][3], 0, 0, 0); \
    acc[mb+3][0] = __builtin_amdgcn_mfma_f32_16x16x32_bf16(A3, B0, acc[mb+3][0], 0, 0, 0); \
    acc[mb+3][1] = __builtin_amdgcn_mfma_f32_16x16x32_bf16(A3, B1, acc[mb+3][1], 0, 0, 0); \
    acc[mb+3][2] = __builtin_amdgcn_mfma_f32_16x16x32_bf16(A3, B2, acc[mb+3][2], 0, 0, 0); \
    acc[mb+3][3] = __builtin_amdgcn_mfma_f32_16x16x32_bf16(A3, B3, acc[mb+3][3], 0, 0, 0);

// ---------------- phase 1: 256x256 tile, BK=32 ring-4, pipelined reads -------
// grid 4096 = 128 rowblocks x 32 codeblocks, 512 thr = 8 waves (2M x 4N)
// LDS 128 KiB: A slots [4][8192] shorts @0, B slots @32768 shorts.
// Paired-line swizzle: rows packed 2/128B-line; slot8=(q+4*(row&1))^(line&7).
// Per step: {issue ph1 reads -> lgkm(4) -> 16 MFMA -> gloads -> lgkm(0) ->
//            16 MFMA -> vmcnt(8) -> barrier -> prefetch ph0(s+1) reads}.
__global__ __launch_bounds__(512, 2) void gemm_argmin_kernel(
        const unsigned short* __restrict__ A2,   // [32768][512]
        const unsigned short* __restrict__ B2,   // [8192][512]
        const float* __restrict__ csq,
        float4* __restrict__ partials) {         // [32 slots][32768 rows]
    extern __shared__ unsigned short S[];        // 131072 B

    const int tid  = threadIdx.x;
    const int w    = tid >> 6;
    const int l    = tid & 63;
    const int wrM  = w >> 2;        // 0..1  -> rows [wrM*128, +128)
    const int wcN  = w & 3;         // 0..3  -> codes [wcN*64, +64)
    const int lcol = l & 15;
    const int g    = l >> 4;

    // bijective XCD swizzle: 4096 wg, 512 per XCD; rb fast (B slice L2-resident)
    const int swz = (blockIdx.x & 7) * 512 + (blockIdx.x >> 3);
    const int rb  = swz & 127;
    const int cbI = swz >> 7;
    const int rowbase  = rb * 256;
    const int codebase = cbI * 256;

    // staging source math (inverse of paired-line swizzle; chunk = 16 rows):
    // lane l -> LDS cell line=c*8+(l>>3), slot8=l&7; that cell must hold
    // global (row = 2*(l>>3) + pre>>2, kq = pre&3), pre = (l&7)^(l>>3).
    const int pre   = (l & 7) ^ (l >> 3);
    const int stRow = 2 * (l >> 3) + (pre >> 2);
    const int stK   = (pre & 3) * 8;

    // read-side lane constants: frag(row=r0+lcol, q=g) at
    // (r0>>1)*64 + (lcol>>1)*64 + slot8*8, slot8 = (g+4*(lcol&1))^((lcol>>1)&7)
    const int lbase = (lcol >> 1) * 64 +
                      (((g + ((lcol & 1) << 2)) ^ ((lcol >> 1) & 7)) * 8);
    const int aoff = wrM * 4096 + lbase;   // + m*512
    const int boff = wcN * 2048 + lbase;   // + n*512

    f32x4 acc[8][4];
    #pragma unroll
    for (int m = 0; m < 8; ++m)
        #pragma unroll
        for (int n = 0; n < 4; ++n) acc[m][n] = (f32x4){0.f, 0.f, 0.f, 0.f};

    // prologue: stage steps 0,1,2 into slots 0,1,2
    #pragma unroll
    for (int s0 = 0; s0 < 3; ++s0) {
        const int ak = AK0(s0), bk = BK0(s0);
        #pragma unroll
        for (int i = 0; i < 2; ++i) {
            const int c = 2 * w + i;
            GLOAD_LDS16(A2 + (size_t)(rowbase + c * 16 + stRow) * KV + ak + stK,
                        &S[s0 * 8192 + c * 512]);
        }
        #pragma unroll
        for (int i = 0; i < 2; ++i) {
            const int c = 2 * w + i;
            GLOAD_LDS16(B2 + (size_t)(codebase + c * 16 + stRow) * KV + bk + stK,
                        &S[32768 + s0 * 8192 + c * 512]);
        }
    }
    // retire slot-0 loads (4 oldest of 12); publish
    asm volatile("s_waitcnt vmcnt(8)" ::: "memory");
    __builtin_amdgcn_sched_barrier(0);
    __builtin_amdgcn_s_barrier();

    // ph0(0) register prefetch from slot 0
    bf16x8 na0, na1, na2, na3, nb0, nb1, nb2, nb3;
    {
        const unsigned short* Ab = &S[0];
        const unsigned short* Bb = &S[32768];
        na0 = RD(Ab, aoff + 0 * 512); na1 = RD(Ab, aoff + 1 * 512);
        na2 = RD(Ab, aoff + 2 * 512); na3 = RD(Ab, aoff + 3 * 512);
        nb0 = RD(Bb, boff + 0 * 512); nb1 = RD(Bb, boff + 1 * 512);
        nb2 = RD(Bb, boff + 2 * 512); nb3 = RD(Bb, boff + 3 * 512);
    }

    #pragma unroll 1
    for (int so = 0; so < NSTEP; so += 4) {
        #pragma unroll
        for (int k = 0; k < 4; ++k) {
            const int s = so + k;
            const unsigned short* Ab = &S[k * 8192];
            int sn = s + 3; if (sn >= NSTEP) sn -= NSTEP;  // wrap: dead stage
            const int snk = (k + 3) & 3;
            const int ak = AK0(sn), bk = BK0(sn);

            // issue ph1 reads (slot k): a4-7 — stay in flight over ph0 MFMA
            bf16x8 a4 = RD(Ab, aoff + 4 * 512);
            bf16x8 a5 = RD(Ab, aoff + 5 * 512);
            bf16x8 a6 = RD(Ab, aoff + 6 * 512);
            bf16x8 a7 = RD(Ab, aoff + 7 * 512);
            // drain only ph0's 8 older reads; keep the 4 new in flight
            asm volatile("s_waitcnt lgkmcnt(4)" ::: "memory");
            __builtin_amdgcn_sched_barrier(0);
            __builtin_amdgcn_s_setprio(1);
            MFMA16(0, na0, na1, na2, na3, nb0, nb1, nb2, nb3);
            __builtin_amdgcn_s_setprio(0);

            // stage step s+3 into ring slot snk (retired 2 steps from now)
            #pragma unroll
            for (int i = 0; i < 2; ++i) {
                const int c = 2 * w + i;
                GLOAD_LDS16(A2 + (size_t)(rowbase + c * 16 + stRow) * KV + ak + stK,
                            &S[snk * 8192 + c * 512]);
            }
            #pragma unroll
            for (int i = 0; i < 2; ++i) {
                const int c = 2 * w + i;
                GLOAD_LDS16(B2 + (size_t)(codebase + c * 16 + stRow) * KV + bk + stK,
                            &S[32768 + snk * 8192 + c * 512]);
            }

            // ph1 reads covered by the 16-MFMA cluster above
            asm volatile("s_waitcnt lgkmcnt(0)" ::: "memory");
            __builtin_amdgcn_sched_barrier(0);
            __builtin_amdgcn_s_setprio(1);
            MFMA16(4, a4, a5, a6, a7, nb0, nb1, nb2, nb3);
            __builtin_amdgcn_s_setprio(0);

            // retire step s+1's 4 loads (issued 2 steps ago); publish slot
            asm volatile("s_waitcnt vmcnt(8)" ::: "memory");
            __builtin_amdgcn_sched_barrier(0);
            __builtin_amdgcn_s_barrier();

            // prefetch ph0(s+1) regs from just-published slot (k+1)&3
            {
                const unsigned short* Ab2 = &S[((k + 1) & 3) * 8192];
                const unsigned short* Bb2 = &S[32768 + ((k + 1) & 3) * 8192];
                na0 = RD(Ab2, aoff + 0 * 512); na1 = RD(Ab2, aoff + 1 * 512);
                na2 = RD(Ab2, aoff + 2 * 512); na3 = RD(Ab2, aoff + 3 * 512);
                nb0 = RD(Bb2, boff + 0 * 512); nb1 = RD(Bb2, boff + 1 * 512);
                nb2 = RD(Bb2, boff + 2 * 512); nb3 = RD(Bb2, boff + 3 * 512);
            }
        }
    }

    // drain dead wrap stages + dangling prefetch before reusing LDS
    asm volatile("s_waitcnt vmcnt(0) lgkmcnt(0)" ::: "memory");
    __builtin_amdgcn_s_barrier();
    asm volatile("" ::: "memory");

    // ---- epilogue: dist = csq - 2*dot, top-2, fold across 4 N-waves in LDS
    float4* T = reinterpret_cast<float4*>(S);    // [256 rows][4 wc]
    #pragma unroll
    for (int m = 0; m < 8; ++m) {
        #pragma unroll
        for (int r = 0; r < 4; ++r) {
            float v1 = 3.4e38f, v2 = 3.4e38f; int i1 = 0x7fffffff;
            #pragma unroll
            for (int n = 0; n < 4; ++n) {
                int code = codebase + wcN * 64 + n * 16 + lcol;
                float d = fmaf(-2.0f, acc[m][n][r], csq[code]);
                float vmax = fmaxf(d, v1);
                v2 = fminf(v2, vmax);
                bool lt = d < v1;
                v1 = lt ? d : v1;
                i1 = lt ? code : i1;
            }
            #pragma unroll
            for (int mask = 1; mask < 16; mask <<= 1) {
                float ov1 = __shfl_xor(v1, mask);
                float ov2 = __shfl_xor(v2, mask);
                int   oi1 = __shfl_xor(i1, mask);
                float nv2 = fminf(fminf(v2, ov2), fmaxf(v1, ov1));
                bool take = (ov1 < v1) || (ov1 == v1 && oi1 < i1);
                v1 = take ? ov1 : v1;
                i1 = take ? oi1 : i1;
                v2 = nv2;
            }
            if (lcol == ((m * 4 + r) & 15)) {
                int rowL = wrM * 128 + m * 16 + g * 4 + r;
                T[rowL * 4 + wcN] = make_float4(v1, v2, __int_as_float(i1), 0.f);
            }
        }
    }
    __syncthreads();
    if (tid < 256) {
        float v1 = 3.4e38f, v2 = 3.4e38f; int i1 = 0x7fffffff;
        #pragma unroll
        for (int s2 = 0; s2 < 4; ++s2) {
            float4 p = T[tid * 4 + s2];
            int pi = __float_as_int(p.z);
            float nv2 = fminf(fminf(v2, p.y), fmaxf(v1, p.x));
            bool take = (p.x < v1) || (p.x == v1 && pi < i1);
            i1 = take ? pi : i1;
            v1 = fminf(v1, p.x);
            v2 = nv2;
        }
        partials[(size_t)cbI * N_ROWS + rowbase + tid] =
            make_float4(v1, v2, __int_as_float(i1), 0.f);
    }
}

// ---------------- reduce 32 slot-major partials per row -> idx or flag -------
__global__ void reduce_kernel(const float4* __restrict__ partials,
                              int* __restrict__ idx,
                              int* __restrict__ flaglist, int* __restrict__ count) {
    int row = blockIdx.x * 256 + threadIdx.x;
    float v1 = 3.4e38f, v2 = 3.4e38f; int i1 = 0x7fffffff;
    #pragma unroll
    for (int s = 0; s < 32; ++s) {
        float4 p = partials[(size_t)s * N_ROWS + row];
        int pi = __float_as_int(p.z);
        float nv2 = fminf(fminf(v2, p.y), fmaxf(v1, p.x));
        bool take = (p.x < v1) || (p.x == v1 && pi < i1);
        i1 = take ? pi : i1;
        v1 = fminf(v1, p.x);
        v2 = nv2;
    }
    if (v2 - v1 > TWO_EPS) {
        idx[row] = i1;
    } else {
        int p = atomicAdd(count, 1);
        flaglist[p] = row;
    }
}

// ---------------- exact fp32 recheck: one BLOCK per flagged row --------------
__global__ __launch_bounds__(256) void recheck_kernel(
        const float* __restrict__ X, const float* __restrict__ C,
        const float* __restrict__ csq, const int* __restrict__ flaglist,
        const int* __restrict__ count, int* __restrict__ idx) {
    __shared__ __align__(16) float xs[DIM];
    __shared__ float rv[4];
    __shared__ int   ri[4];
    const int nf = *count;
    const int tid = threadIdx.x;

    for (int b = blockIdx.x; b < nf; b += gridDim.x) {
        const int row = flaglist[b];
        __syncthreads();
        if (tid < 64)
            reinterpret_cast<float4*>(xs)[tid] =
                reinterpret_cast<const float4*>(X + (size_t)row * DIM)[tid];
        __syncthreads();

        float best = 3.4e38f; int bi = 0x7fffffff;
        for (int j = 0; j < 32; j += 2) {
            const int c0 = tid + j * 256;
            const int c1 = c0 + 256;
            const float* p0 = C + (size_t)c0 * DIM;
            const float* p1 = C + (size_t)c1 * DIM;
            float d0 = 0.f, d1 = 0.f;
            #pragma unroll 8
            for (int d = 0; d < DIM; d += 4) {
                float4 a  = *reinterpret_cast<const float4*>(xs + d);
                float4 q0 = *reinterpret_cast<const float4*>(p0 + d);
                float4 q1 = *reinterpret_cast<const float4*>(p1 + d);
                d0 = fmaf(a.x, q0.x, d0); d0 = fmaf(a.y, q0.y, d0);
                d0 = fmaf(a.z, q0.z, d0); d0 = fmaf(a.w, q0.w, d0);
                d1 = fmaf(a.x, q1.x, d1); d1 = fmaf(a.y, q1.y, d1);
                d1 = fmaf(a.z, q1.z, d1); d1 = fmaf(a.w, q1.w, d1);
            }
            float dist0 = fmaf(-2.f, d0, csq[c0]);
            float dist1 = fmaf(-2.f, d1, csq[c1]);
            if (dist0 < best) { best = dist0; bi = c0; }
            if (dist1 < best) { best = dist1; bi = c1; }
        }
        #pragma unroll
        for (int m = 1; m < 64; m <<= 1) {
            float ov = __shfl_xor(best, m);
            int   oi = __shfl_xor(bi, m);
            if (ov < best || (ov == best && oi < bi)) { best = ov; bi = oi; }
        }
        if ((tid & 63) == 0) { rv[tid >> 6] = best; ri[tid >> 6] = bi; }
        __syncthreads();
        if (tid == 0) {
            #pragma unroll
            for (int wv = 1; wv < 4; ++wv) {
                if (rv[wv] < best || (rv[wv] == best && ri[wv] < bi)) {
                    best = rv[wv]; bi = ri[wv];
                }
            }
            idx[row] = bi;
        }
    }
}

// ---------------- gather: one wave per row, write both halves ----------------
__global__ void gather_kernel(const float* __restrict__ C,
                              const int* __restrict__ idx,
                              float* __restrict__ out) {
    const size_t half = (size_t)N_ROWS * DIM;
    int gtid = blockIdx.x * blockDim.x + threadIdx.x;
    int lane = threadIdx.x & 63;
    int wave = gtid >> 6;
    int nwaves = (gridDim.x * blockDim.x) >> 6;
    for (int row = wave; row < N_ROWS; row += nwaves) {
        int id = idx[row];
        float4 v = reinterpret_cast<const float4*>(C + (size_t)id * DIM)[lane];
        reinterpret_cast<float4*>(out + (size_t)row * DIM)[lane] = v;
        reinterpret_cast<float4*>(out + half + (size_t)row * DIM)[lane] = v;
    }
}

extern "C" void kernel_launch(void* const* d_in, const int* in_sizes, int n_in,
                              void* d_out, int out_size, void* d_ws, size_t ws_size,
                              hipStream_t stream) {
    const float* z  = (const float*)d_in[0];   // (32,1024,256) fp32
    const float* cb = (const float*)d_in[1];   // (8192,256)    fp32
    float* out = (float*)d_out;

    // big scratch in d_out (fully overwritten by gather at the end):
    char* sc = (char*)d_out;
    unsigned short* A2 = (unsigned short*)(sc);               // 33,554,432 B
    unsigned short* B2 = (unsigned short*)(sc + 33554432);    //  8,388,608 B
    float4* partials   = (float4*)(sc + 41943040);            // 16,777,216 B

    // small scratch in d_ws (~295 KB):
    float* csq    = (float*)d_ws;                              // 32 KB
    int*   idx    = (int*)((char*)d_ws + 32768);               // 128 KB
    int*   flags  = (int*)((char*)d_ws + 163840);              // 128 KB
    int*   count  = (int*)((char*)d_ws + 294912);              // 4 B

    static bool attr_done = false;
    if (!attr_done) {
        hipFuncSetAttribute((const void*)gemm_argmin_kernel,
                            hipFuncAttributeMaxDynamicSharedMemorySize, 131072);
        attr_done = true;
    }

    init_kernel<<<1, 1, 0, stream>>>(count);
    split_pack_kernel<<<(N_ROWS * DIM) / (256 * 8), 256, 0, stream>>>(z, A2);
    split_pack_kernel<<<(N_CODES * DIM) / (256 * 8), 256, 0, stream>>>(cb, B2);
    csq_kernel<<<(N_CODES * 64) / 256, 256, 0, stream>>>(cb, csq);
    gemm_argmin_kernel<<<4096, 512, 131072, stream>>>(A2, B2, csq, partials);
    reduce_kernel<<<N_ROWS / 256, 256, 0, stream>>>(partials, idx, flags, count);
    recheck_kernel<<<512, 256, 0, stream>>>(z, cb, csq, flags, count, idx);
    gather_kernel<<<2048, 256, 0, stream>>>(cb, idx, out);
}